// Round 8
// baseline (371.160 us; speedup 1.0000x reference)
//
#include <hip/hip_runtime.h>
#include <math.h>

// Problem constants (fixed by the reference file)
#define BATCH 16
#define CHAN  64
#define Hh    256
#define Ww    256
#define HP    128     // pooled H
#define WP    128     // pooled W
#define TH    64      // strip rows per block (full 256-col width)
#define CHs   66      // canvas rows  (image rows y0-1 .. y0+64)
#define CWs   258     // canvas cols  (image cols -1 .. 256)
#define S     260     // canvas row stride in words (16B-aligned, 260%32=4)
#define NW4   (CHs * (S / 4))   // 4290 uint4 fill units
#define NCAND (34 * 128)        // staged pooled candidates per strip

typedef unsigned int u32;
typedef float vfloat4 __attribute__((ext_vector_type(4)));

// One block = one 64x256 full-width output strip. 1024 threads, 16 waves,
// 68.6 KB LDS -> 2 blocks/CU = 32 waves/CU.
//
// Why strips: pooled staging is 34 FULL 512B-aligned rows -> zero cache-line
// segment waste and no reliance on cross-block L2 sharing for halo lines.
// Over-fetch is exactly the 34/32 vertical halo (~1.06x).
//
// phase 0: border-aware zero-fill (single writer per uint4 -> no init race).
//          Cols 0/257 (image cols -1/256) and out-of-image strip rows get
//          -inf (reduce_window 'same' padding); the rest 0.0f.
// phase 1: coalesced prov/f loads (row-clamped at image edges; clamped
//          duplicates replay an identical (q,f) candidate -> atomicMax is
//          idempotent -> no validity mask needed). atomicMax(cell, q+1):
//          winner = max flat pooled index = numpy last-write-wins.
// phase 2: winner (cell == q+1) overwrites with f32 bits. Race safety:
//          N(0,1) float bits never fall in [1, 16385] (denormal range).
// stage 2: 3x3 max; thread owns 4x4 outputs, reads 6x6 patch; the float4
//          LDS pattern covers all 32 banks evenly (2/bank/phase = free).
//          Full-row nontemporal float4 stores (1 KB per wave-instruction).
__global__ __launch_bounds__(1024, 8) void unpool_dilate_kernel(
    const float* __restrict__ f, const int* __restrict__ prov,
    float* __restrict__ out)
{
    __shared__ __align__(16) u32 s[CHs * S];     // 68,640 B

    const int tid = threadIdx.x;
    const int ty  = blockIdx.x;                  // 0..3 strip index
    const int bc  = blockIdx.y;                  // 0..1023 (b*C + c)
    const int y0  = ty * TH;
    const size_t in_base = (size_t)bc * (HP * WP);

    // ---- phase 1a: issue all candidate loads first (latency overlap) ----
    const int pi0 = ty * 32 - 1;                 // staged row 0 -> pooled row
    u32   m_key[5];
    int   m_p[5];
    float m_f[5];
    #pragma unroll
    for (int it = 0; it < 5; ++it) {
        const int k = tid + it * 1024;
        m_key[it] = 0;                           // 0 = inactive slot
        if (k < NCAND) {
            const int ki = k >> 7;               // staged row
            const int kj = k & 127;              // pooled col
            const int pi = min(max(pi0 + ki, 0), HP - 1);  // edge clamp
            const int q  = (pi << 7) + kj;
            m_key[it] = (u32)(q + 1);
            m_p[it]   = prov[in_base + q];       // full-row coalesced
            m_f[it]   = f[in_base + q];
        }
    }

    // ---- phase 0: border-aware fill, single writer per uint4 ----
    {
        const u32 NI = 0xFF800000u;              // -inf bits
        uint4* p4 = (uint4*)s;
        #pragma unroll
        for (int it = 0; it < 5; ++it) {
            const int idx = tid + it * 1024;
            if (idx < NW4) {
                const int row = idx / 65;        // compile-time magic mul
                const int c4  = (idx - row * 65) * 4;   // word col base
                const bool rinf = (ty == 0 && row == 0) | (ty == 3 && row == CHs - 1);
                uint4 v;
                v.x = (rinf | (c4 == 0))   ? NI : 0u;   // col 0  = image col -1
                v.y = (rinf | (c4 == 256)) ? NI : 0u;   // word 257 = image col 256
                v.z = rinf ? NI : 0u;
                v.w = rinf ? NI : 0u;
                p4[idx] = v;
            }
        }
    }
    __syncthreads();

    // ---- phase 1b: atomicMax keys (row check only; cols always in-canvas) ----
    int m_li[5];
    #pragma unroll
    for (int it = 0; it < 5; ++it) {
        m_li[it] = -1;
        if (m_key[it]) {
            const int p  = m_p[it];
            const int lr = (p >> 8) - y0 + 1;    // canvas row (Ww == 256)
            if ((unsigned)lr < CHs) {
                const int li = lr * S + (p & 255) + 1;
                m_li[it] = li;
                atomicMax(&s[li], m_key[it]);
            }
        }
    }
    __syncthreads();

    // ---- phase 2: winners overwrite their key with the f32 value bits ----
    #pragma unroll
    for (int it = 0; it < 5; ++it) {
        if (m_li[it] >= 0 && s[m_li[it]] == m_key[it])
            s[m_li[it]] = __float_as_uint(m_f[it]);
    }
    __syncthreads();

    // ---- stage 2: 3x3 max; thread owns 4x4 outputs, reads 6x6 patch ----
    const float* sf = (const float*)s;
    const int tr = tid >> 6;                     // 0..15
    const int tc = tid & 63;                     // 0..63
    const int c0 = 4 * tc;                       // canvas col base (= out col)

    float h0[4], h1[4];                          // horizontal 3-max of prior rows
    const size_t obase = (size_t)bc * (Hh * Ww) + (size_t)(y0 + 4 * tr) * Ww + c0;

    #pragma unroll
    for (int r = 0; r < 6; ++r) {
        const float* row = sf + (4 * tr + r) * S + c0;
        const float4 a = *(const float4*)row;        // canvas cols c0..c0+3
        const float2 b = *(const float2*)(row + 4);  // canvas cols c0+4..c0+5
        float h[4];
        h[0] = fmaxf(fmaxf(a.x, a.y), a.z);          // -> v_max3_f32
        h[1] = fmaxf(fmaxf(a.y, a.z), a.w);
        h[2] = fmaxf(fmaxf(a.z, a.w), b.x);
        h[3] = fmaxf(fmaxf(a.w, b.x), b.y);
        if (r >= 2) {
            vfloat4 res;
            res.x = fmaxf(fmaxf(h0[0], h1[0]), h[0]);
            res.y = fmaxf(fmaxf(h0[1], h1[1]), h[1]);
            res.z = fmaxf(fmaxf(h0[2], h1[2]), h[2]);
            res.w = fmaxf(fmaxf(h0[3], h1[3]), h[3]);
            __builtin_nontemporal_store(res, (vfloat4*)(out + obase + (size_t)(r - 2) * Ww));
        }
        #pragma unroll
        for (int j = 0; j < 4; ++j) { h0[j] = h1[j]; h1[j] = h[j]; }
    }
}

extern "C" void kernel_launch(void* const* d_in, const int* in_sizes, int n_in,
                              void* d_out, int out_size, void* d_ws, size_t ws_size,
                              hipStream_t stream) {
    const float* f    = (const float*)d_in[0];
    const int*   prov = (const int*)d_in[1];
    // d_in[2]=h, d_in[3]=w fixed at 256 by the reference; hardcoded.
    float* out = (float*)d_out;

    dim3 grid(Hh / TH, BATCH * CHAN);            // (4, 1024) strips
    unpool_dilate_kernel<<<grid, 1024, 0, stream>>>(f, prov, out);
}

// Round 9
// 362.575 us; speedup vs baseline: 1.0237x; 1.0237x over previous
//
#include <hip/hip_runtime.h>
#include <math.h>

// Problem constants (fixed by the reference file)
#define BATCH 16
#define CHAN  64
#define Hh    256
#define Ww    256
#define HP    128     // pooled H
#define WP    128     // pooled W
#define TH    64      // output tile rows per block
#define TW    64      // output tile cols per block
#define CH    66      // canvas rows (halo 1)
#define CW    66      // canvas cols
#define CS    68      // canvas row stride in words (keeps 16B alignment)

typedef unsigned int u32;
typedef float vfloat4 __attribute__((ext_vector_type(4)));

// One block = one 64x64 output tile of one (b,c) image. 256 threads,
// 17.95 KB LDS -> 8 blocks/CU = 32 waves/CU (residency is what buys the
// barrier-latency overlap: r8's 2-block/CU strip variant regressed).
//
// Single u32 LDS canvas, three phases:
//   phase 0: border-aware zero-fill, SINGLE WRITER per uint4 (r5 had a
//            cross-wave write race between fill and border writes).
//            0.0f in-image, -inf (0xFF800000) for reduce_window padding.
//   phase 1: branchless pipelined loads of prov+f (clamped addresses,
//            m_key==0 sentinel for inactive slots), then
//            atomicMax(cell, q+1): winner = max flat pooled index
//            = numpy last-write-wins scatter semantics.
//   phase 2: winner (cell == q+1) overwrites cell with its f32 bits. Every
//            keyed cell has exactly one winner, so no key survives. Race
//            safety: float bits of N(0,1) values are never in [1,16385]
//            (that range is denormals ~1e-41), so a loser can't mistake a
//            value for its key.
//   stage 2: 3x3 windowed max; thread owns a 4x4 output block, reads a
//            6x6 f32 patch (2.25 LDS words/px), nontemporal float4 stores.
__global__ __launch_bounds__(256, 8) void unpool_dilate_kernel(
    const float* __restrict__ f, const int* __restrict__ prov,
    float* __restrict__ out)
{
    __shared__ __align__(16) u32 s[CH * CS];   // 4488 words = 17.95 KB

    const int tid = threadIdx.x;
    const int bc  = blockIdx.y;                // 0..1023 (b*C + c)
    const int ty  = blockIdx.x >> 2;           // 4x4 tiles per image
    const int tx  = blockIdx.x & 3;
    const int y0  = ty * TH;
    const int x0  = tx * TW;

    // ---- candidate pooled region: up to 34x34, guarded at image edges ----
    const int pi_min = (ty == 0) ? 0 : (ty * 32 - 1);
    const int pj_min = (tx == 0) ? 0 : (tx * 32 - 1);
    const int pi_max = min(HP - 1, ty * 32 + 32);
    const int pj_max = min(WP - 1, tx * 32 + 32);
    const size_t in_base = (size_t)bc * (HP * WP);

    // ---- phase 1a: branchless pipelined loads (issue all 10 loads early) ----
    u32   m_key[5];
    float m_f[5];
    int   m_p[5];
    #pragma unroll
    for (int it = 0; it < 5; ++it) {
        m_key[it] = 0u;                        // sentinel: inactive
        const int k = tid + it * 256;
        if (k < 34 * 34) {
            const int ki = k / 34;             // compile-time magic mul
            const int kj = k - ki * 34;
            const bool valid = (pi_min + ki <= pi_max) & (pj_min + kj <= pj_max);
            const int pi = min(pi_min + ki, pi_max);   // clamped -> in-bounds
            const int pj = min(pj_min + kj, pj_max);
            const int q  = pi * WP + pj;
            m_key[it] = valid ? (u32)(q + 1) : 0u;
            m_p[it]   = prov[in_base + q];     // loads issued regardless of
            m_f[it]   = f[in_base + q];        // validity (clamped = safe)
        }
    }

    // ---- phase 0: border-aware fill, single writer per uint4 ----
    {
        const u32 NI = 0xFF800000u;            // -inf bits
        uint4* p4 = (uint4*)s;
        #pragma unroll
        for (int it = 0; it < 5; ++it) {
            const int idx = tid + it * 256;
            if (idx < (CH * CS) / 4) {         // 1122 uint4 units
                const int row = idx / 17;      // CS/4 = 17 -> magic mul
                const int c4w = (idx - row * 17) * 4;   // word col base
                const bool rinf = ((ty == 0) & (row == 0)) |
                                  ((ty == 3) & (row == CH - 1));
                uint4 v;
                v.x = (rinf | ((tx == 0) & (c4w == 0)))  ? NI : 0u;  // col 0
                v.y = (rinf | ((tx == 3) & (c4w == 64))) ? NI : 0u;  // col 65
                v.z = rinf ? NI : 0u;
                v.w = rinf ? NI : 0u;
                p4[idx] = v;
            }
        }
    }
    __syncthreads();

    // ---- phase 1b: atomicMax keys ----
    int m_li[5];
    #pragma unroll
    for (int it = 0; it < 5; ++it) {
        m_li[it] = -1;
        if (m_key[it]) {
            const int p  = m_p[it];
            const int lr = (p >> 8) - y0 + 1;  // canvas row (Ww == 256)
            const int lc = (p & 255) - x0 + 1; // canvas col
            if ((unsigned)lr < CH && (unsigned)lc < CW) {
                const int li = lr * CS + lc;
                m_li[it] = li;
                atomicMax(&s[li], m_key[it]);
            }
        }
    }
    __syncthreads();

    // ---- phase 2: winners overwrite their key with the f32 value bits ----
    #pragma unroll
    for (int it = 0; it < 5; ++it) {
        if (m_li[it] >= 0 && s[m_li[it]] == m_key[it])
            s[m_li[it]] = __float_as_uint(m_f[it]);
    }
    __syncthreads();

    // ---- stage 2: 3x3 max; thread owns 4x4 outputs, reads 6x6 patch ----
    const float* sf = (const float*)s;
    const int tr = tid >> 4;                  // 0..15
    const int tc = tid & 15;                  // 0..15
    const int r0 = 4 * tr;                    // canvas row base (== output row)
    const int c0 = 4 * tc;

    float h0[4], h1[4];                       // horizontal 3-max of prior rows
    const size_t obase = (size_t)bc * (Hh * Ww) + (size_t)(y0 + r0) * Ww + (x0 + c0);

    #pragma unroll
    for (int r = 0; r < 6; ++r) {
        const float* row = sf + (r0 + r) * CS + c0;
        const float4 a = *(const float4*)row;        // cols c0..c0+3 (16B aligned)
        const float2 b = *(const float2*)(row + 4);  // cols c0+4..c0+5
        float h[4];
        h[0] = fmaxf(fmaxf(a.x, a.y), a.z);          // -> v_max3_f32
        h[1] = fmaxf(fmaxf(a.y, a.z), a.w);
        h[2] = fmaxf(fmaxf(a.z, a.w), b.x);
        h[3] = fmaxf(fmaxf(a.w, b.x), b.y);
        if (r >= 2) {
            vfloat4 res;
            res.x = fmaxf(fmaxf(h0[0], h1[0]), h[0]);
            res.y = fmaxf(fmaxf(h0[1], h1[1]), h[1]);
            res.z = fmaxf(fmaxf(h0[2], h1[2]), h[2]);
            res.w = fmaxf(fmaxf(h0[3], h1[3]), h[3]);
            __builtin_nontemporal_store(res, (vfloat4*)(out + obase + (size_t)(r - 2) * Ww));
        }
        #pragma unroll
        for (int j = 0; j < 4; ++j) { h0[j] = h1[j]; h1[j] = h[j]; }
    }
}

extern "C" void kernel_launch(void* const* d_in, const int* in_sizes, int n_in,
                              void* d_out, int out_size, void* d_ws, size_t ws_size,
                              hipStream_t stream) {
    const float* f    = (const float*)d_in[0];
    const int*   prov = (const int*)d_in[1];
    // d_in[2]=h, d_in[3]=w fixed at 256 by the reference; hardcoded.
    float* out = (float*)d_out;

    dim3 grid((Hh / TH) * (Ww / TW), BATCH * CHAN);  // (16, 1024)
    unpool_dilate_kernel<<<grid, 256, 0, stream>>>(f, prov, out);
}